// Round 3
// baseline (198.167 us; speedup 1.0000x reference)
//
#include <hip/hip_runtime.h>
#include <hip/hip_fp16.h>

constexpr int N_CLUSTERS   = 131072;
constexpr int N_CENTROIDS  = 256;
constexpr int D_FEAT       = 64;

constexpr int THREADS        = 512;   // 8 waves
constexpr int ROWS_PER_BLOCK = 128;   // 16 clusters per wave

// Finite-in-bf16 sentinel for masked (cross-batch) outputs; see round-2 note.
#define MASK_VAL (-1.0e30f)

typedef __attribute__((ext_vector_type(8))) short bf16x8;   // 8 bf16 (4 VGPRs)
typedef __attribute__((ext_vector_type(4))) float f32x4;    // MFMA C/D
typedef __attribute__((ext_vector_type(2))) __fp16 h2;      // cvt_pkrtz result
typedef __attribute__((ext_vector_type(2))) _Float16 f16x2; // native f16 math

// fp32 pair -> packed bf16 via ONE v_perm_b32 (truncation; fine at inf thr).
static __device__ inline unsigned pk2t(float a, float b) {
    return __builtin_amdgcn_perm(__float_as_uint(b), __float_as_uint(a), 0x07060302u);
}
// fp32 x4 -> packed 4 x f16 in one u32 (2x v_cvt_pkrtz_f16_f32 + 1 v_perm)
static __device__ inline unsigned pk4h(float a, float b, float c, float d) {
    h2 p01 = __builtin_amdgcn_cvt_pkrtz(a, b);
    h2 p23 = __builtin_amdgcn_cvt_pkrtz(c, d);
    unsigned lo, hi;
    __builtin_memcpy(&lo, &p01, 4);
    __builtin_memcpy(&hi, &p23, 4);
    return __builtin_amdgcn_perm(hi, lo, 0x05040100u);
}
static __device__ inline float h2f_lo(unsigned u) {
    return __half2float(__ushort_as_half((unsigned short)(u & 0xFFFFu)));
}
static __device__ inline float h2f_hi(unsigned u) {
    return __half2float(__ushort_as_half((unsigned short)(u >> 16)));
}

// ROUND 13 — DIAGNOSTIC BUILD. The hot kernel has never appeared in the
// rocprof top-5 (it is ~71 us, just under the 79-84 us poison fills), so we
// have no counters for it and two predictions in a row have missed. This
// build runs the compute+store body TWICE inside one dispatch (identical
// values stored twice -> bit-identical output, correctness preserved). The
// dispatch becomes ~142 us -> #1 in top-5 -> full counter row:
//   FETCH_SIZE >> 100 MB  => write-allocate on 64-B-sector stores (H-A)
//   VGPR_Count==64 / low OccupancyPercent => launch-bounds spill (H-B)
//   VALUBusy > 60%        => VALU-bound pass 1 / epilogue (H-C)
// The rep loop is guarded against CSE/DSE with opaque "+v" asm + "memory"
// clobber and #pragma unroll 1.
__global__ __launch_bounds__(THREADS, 8)
void instance_head_kernel(const int*   __restrict__ clu_coords,   // [N,4] {b,x,y,z}
                          const float* __restrict__ clu_feats,    // [N,64]
                          const int*   __restrict__ cen_coords,   // [M,4]
                          const float* __restrict__ cen_feats,    // [M,64]
                          float*       __restrict__ out)          // [N,M]
{
    __shared__ unsigned Bl[16 * 2 * 64 * 4];   // 32 KB, centroid-feat fragments
    __shared__ uint2    pcch[N_CENTROIDS];     // {x,y} f16 pair | {z,b} f16 pair

    const int t    = threadIdx.x;
    const int lane = t & 63;
    const int wave = __builtin_amdgcn_readfirstlane(t >> 6);
    const int m    = lane & 15;
    const int quad = lane >> 4;
    const int r0w  = blockIdx.x * ROWS_PER_BLOCK + wave * 16;

    // ---- B operand: this lane's cluster feats (coalesced fp32 loads) ----
    const float* bptr = clu_feats + (size_t)(r0w + m) * D_FEAT + quad * 8;
    const float4 bL0 = *(const float4*)(bptr);
    const float4 bH0 = *(const float4*)(bptr + 4);
    const float4 bL1 = *(const float4*)(bptr + 32);
    const float4 bH1 = *(const float4*)(bptr + 36);

    // ---- stage centroid feats: fp32 -> bf16, fragment order, XOR-swizzled ----
    #pragma unroll
    for (int i = 0; i < 4; ++i) {
        const int q = t + i * THREADS;        // octet: centroid n, feature-octet o
        const int n = q >> 3, o = q & 7;
        const float4 g0 = ((const float4*)cen_feats)[q * 2];
        const float4 g1 = ((const float4*)cen_feats)[q * 2 + 1];
        uint4 d;
        d.x = pk2t(g0.x, g0.y); d.y = pk2t(g0.z, g0.w);
        d.z = pk2t(g1.x, g1.y); d.w = pk2t(g1.z, g1.w);
        const int tile = n >> 4;
        const int np   = n & 15;
        const int f    = o >> 2;
        const int lp   = (np | ((o & 3) << 4)) ^ o;   // XOR bank swizzle (r5-verified)
        ((uint4*)Bl)[(tile * 2 + f) * 64 + lp] = d;
    }
    // centroid coords packed to f16 pairs (exact: ints < 128)
    if (t < N_CENTROIDS) {
        const int4 c = ((const int4*)cen_coords)[t];   // {b,x,y,z}
        f16x2 xy, zb;
        xy.x = (_Float16)c.y; xy.y = (_Float16)c.z;    // {x, y}
        zb.x = (_Float16)c.w; zb.y = (_Float16)c.x;    // {z, b}
        uint2 p;
        __builtin_memcpy(&p.x, &xy, 4);
        __builtin_memcpy(&p.y, &zb, 4);
        pcch[t] = p;
    }

    // ---- this lane's cluster coords (one row), packed f16 (as u32 for asm) ----
    const int4 rc = ((const int4*)clu_coords)[r0w + m];   // {b,x,y,z}
    unsigned cu0, cu1;
    {
        f16x2 rxy, rzb;
        rxy.x = (_Float16)rc.y; rxy.y = (_Float16)rc.z;
        rzb.x = (_Float16)rc.w; rzb.y = (_Float16)rc.x;
        __builtin_memcpy(&cu0, &rxy, 4);
        __builtin_memcpy(&cu1, &rzb, 4);
    }

    // ---- convert B frags to bf16 (perm-truncate) ----
    union { uint4 u; bf16x8 v; } b0, b1;
    b0.u.x = pk2t(bL0.x, bL0.y); b0.u.y = pk2t(bL0.z, bL0.w);
    b0.u.z = pk2t(bH0.x, bH0.y); b0.u.w = pk2t(bH0.z, bH0.w);
    b1.u.x = pk2t(bL1.x, bL1.y); b1.u.y = pk2t(bL1.z, bL1.w);
    b1.u.z = pk2t(bH1.x, bH1.y); b1.u.w = pk2t(bH1.z, bH1.w);

    __syncthreads();

    const int sl0 = lane ^ quad;              // inverse swizzle, frag 0
    const int sl1 = sl0 ^ 4;                  // frag 1

    #pragma unroll 1
    for (int rep = 0; rep < 2; ++rep) {
        // Opaque inputs: forces full recompute of both passes each rep;
        // "memory" blocks load-CSE and cross-rep dead-store elimination.
        asm volatile("" : "+v"(cu0), "+v"(cu1),
                          "+v"(b0.u.x), "+v"(b0.u.y), "+v"(b0.u.z), "+v"(b0.u.w),
                          "+v"(b1.u.x), "+v"(b1.u.y), "+v"(b1.u.z), "+v"(b1.u.w)
                     :: "memory");
        f16x2 rxy, rzb;
        __builtin_memcpy(&rxy, &cu0, 4);
        __builtin_memcpy(&rzb, &cu1, 4);

        // ---- pass 1: exp(-dist), packed 4 x f16 per reg; f32 row sum ----
        unsigned u16[16];
        float rsum = 0.f;
        #pragma unroll
        for (int tt = 0; tt < 16; ++tt) {
            float uu[4];
            #pragma unroll
            for (int i = 0; i < 4; ++i) {
                const uint2 cw = pcch[tt * 16 + quad * 4 + i];   // ds_read_b64
                f16x2 cxy, czb;
                __builtin_memcpy(&cxy, &cw.x, 4);
                __builtin_memcpy(&czb, &cw.y, 4);
                const f16x2 dxy = cxy - rxy;                     // packed f16 sub, exact
                const f16x2 dzb = czb - rzb;                     // .x = dz, .y = db
                const float dx = (float)dxy.x, dy = (float)dxy.y, dz = (float)dzb.x;
                const float d2   = fmaf(dx, dx, fmaf(dy, dy, dz * dz));   // exact
                const float dist = fmaxf(__builtin_sqrtf(d2), 0.1f);
                const float e    = __expf(-dist);
                const bool  same = (dzb.y == (_Float16)0);
                rsum += same ? e : 0.f;
                uu[i] = same ? e : -1.0f;
            }
            u16[tt] = pk4h(uu[0], uu[1], uu[2], uu[3]);
        }
        rsum += __shfl_xor(rsum, 16, 64);
        rsum += __shfl_xor(rsum, 32, 64);
        const float inv = (rsum > 1e-37f) ? __builtin_amdgcn_rcpf(rsum) : 0.f;

        // ---- pass 2: MFMA + fused epilogue + float4 stores ----
        float* obase = out + (size_t)(r0w + m) * N_CENTROIDS + quad * 4;
        #pragma unroll
        for (int tt = 0; tt < 16; ++tt) {
            const bf16x8 aC0 = *(const bf16x8*)&Bl[((tt * 2 + 0) * 64 + sl0) * 4];
            const bf16x8 aC1 = *(const bf16x8*)&Bl[((tt * 2 + 1) * 64 + sl1) * 4];
            f32x4 acc = {0.f, 0.f, 0.f, 0.f};
            acc = __builtin_amdgcn_mfma_f32_16x16x32_bf16(aC0, b0.v, acc, 0, 0, 0);
            acc = __builtin_amdgcn_mfma_f32_16x16x32_bf16(aC1, b1.v, acc, 0, 0, 0);

            const unsigned up = u16[tt];
            const unsigned uq = u16[tt] >> 16;
            float uu[4];
            uu[0] = h2f_lo(up); uu[1] = h2f_hi(up);
            uu[2] = h2f_lo(uq); uu[3] = h2f_hi(uq);
            float4 o;
            #pragma unroll
            for (int i = 0; i < 4; ++i) {
                float w = acc[i] * (fmaxf(uu[i], 0.f) * inv);
                w = fminf(fmaxf(w, -10.f), 10.f);
                (&o.x)[i] = (uu[i] < 0.f) ? MASK_VAL : w;
            }
            *(float4*)(obase + tt * 16) = o;
        }
    }
}

extern "C" void kernel_launch(void* const* d_in, const int* in_sizes, int n_in,
                              void* d_out, int out_size, void* d_ws, size_t ws_size,
                              hipStream_t stream) {
    const int*   clu_coords = (const int*)  d_in[0];
    const float* clu_feats  = (const float*)d_in[1];
    const int*   cen_coords = (const int*)  d_in[2];
    const float* cen_feats  = (const float*)d_in[3];
    float* out = (float*)d_out;

    dim3 grid(N_CLUSTERS / ROWS_PER_BLOCK);   // 1024 blocks
    dim3 block(THREADS);                      // 512 threads = 8 waves
    instance_head_kernel<<<grid, block, 0, stream>>>(
        clu_coords, clu_feats, cen_coords, cen_feats, out);
}

// Round 4
// 175.189 us; speedup vs baseline: 1.1312x; 1.1312x over previous
//
#include <hip/hip_runtime.h>
#include <hip/hip_fp16.h>

constexpr int N_CLUSTERS   = 131072;
constexpr int N_CENTROIDS  = 256;
constexpr int D_FEAT       = 64;

constexpr int THREADS        = 512;   // 8 waves
constexpr int ROWS_PER_BLOCK = 128;   // 16 clusters per wave

// Finite-in-bf16 sentinel for masked (cross-batch) outputs.
#define MASK_VAL (-1.0e30f)
// Mask detector: true d^2 <= 3*127^2 = 48387; cross-batch adds W*(db)^2 >= 2^17.
#define TH_MASK  (65536.0f)

typedef __attribute__((ext_vector_type(8))) short bf16x8;   // 8 bf16 (4 VGPRs)
typedef __attribute__((ext_vector_type(4))) float f32x4;    // MFMA C/D
typedef __attribute__((ext_vector_type(2))) __fp16 h2;      // cvt_pkrtz result

// fp32 pair -> packed bf16 via ONE v_perm_b32 (truncation; exact for the
// integer-valued inputs used here).
static __device__ inline unsigned pk2t(float a, float b) {
    return __builtin_amdgcn_perm(__float_as_uint(b), __float_as_uint(a), 0x07060302u);
}
// fp32 x4 -> packed 4 x f16 in one u32 (2x v_cvt_pkrtz_f16_f32 + 1 v_perm)
static __device__ inline unsigned pk4h(float a, float b, float c, float d) {
    h2 p01 = __builtin_amdgcn_cvt_pkrtz(a, b);
    h2 p23 = __builtin_amdgcn_cvt_pkrtz(c, d);
    unsigned lo, hi;
    __builtin_memcpy(&lo, &p01, 4);
    __builtin_memcpy(&hi, &p23, 4);
    return __builtin_amdgcn_perm(hi, lo, 0x05040100u);
}
static __device__ inline float h2f_lo(unsigned u) {
    return __half2float(__ushort_as_half((unsigned short)(u & 0xFFFFu)));
}
static __device__ inline float h2f_hi(unsigned u) {
    return __half2float(__ushort_as_half((unsigned short)(u >> 16)));
}

// ROUND 14 — MFMA-computed distances. Round-13 diagnostic (body x2) showed
// VALUBusy 79.8%, MfmaUtil 4.2%, hbm 3.5 TB/s: the kernel is VALU-bound in
// pass-1's per-element coordinate math (~150 VALU-cy/element measured).
// Fix: d^2 (+ batch mask) via one bf16 MFMA per 16-centroid tile, using a
// 10-slot K layout (A = centroid side, B = cluster side, W = 2^17):
//   k0..2: -2{x,y,z}_cen | {x,y,z}_clu      -> -2 c.p
//   k3   : -2W*b_cen     | b_clu            -> -2W b_c b_p
//   k4,5 : cn_hi, cn_lo  | 1, 1             -> |c|^2       (hi/lo bf16 split)
//   k6   : W*b_cen^2     | 1
//   k7,8 : 1, 1          | pn_hi, pn_lo     -> |p|^2
//   k9   : 1             | W*b_clu^2
// Sum = |c-p|^2 + W*(b_c-b_p)^2, EXACT: all inputs are bf16-exact integers
// (or hi/lo splits with lo < 256), all products < 2^24, f32 accum exact.
// Cross-batch => d2 >= 2^17 => exp underflows to +0 (rsum add is then
// unconditional) and (d2 < TH_MASK) yields the output mask bit.
// Per-element pass-1 VALU drops to {sqrt, exp(trans), max, mul, cmp,
// cndmask, add}; pcch LDS reads and f16 coord packing are deleted.
//
// LDS: Bl 32768 B + Atab 4096 B = 36864 B -> 4 blocks/CU (147 KB of 160),
// x 8 waves = 32 waves/CU cap via __launch_bounds__(512, 8).
__global__ __launch_bounds__(THREADS, 8)
void instance_head_kernel(const int*   __restrict__ clu_coords,   // [N,4] {b,x,y,z}
                          const float* __restrict__ clu_feats,    // [N,64]
                          const int*   __restrict__ cen_coords,   // [M,4]
                          const float* __restrict__ cen_feats,    // [M,64]
                          float*       __restrict__ out)          // [N,M]
{
    __shared__ unsigned Bl[16 * 2 * 64 * 4];   // 32 KB, centroid-feat fragments
    __shared__ uint4    Atab[N_CENTROIDS];     // 4 KB, centroid coord A-frags

    const int t    = threadIdx.x;
    const int lane = t & 63;
    const int wave = __builtin_amdgcn_readfirstlane(t >> 6);
    const int m    = lane & 15;
    const int quad = lane >> 4;
    const int r0w  = blockIdx.x * ROWS_PER_BLOCK + wave * 16;

    // ---- B operand: this lane's cluster feats (coalesced fp32 loads) ----
    // frag f, lane: B[col = m][k = f*32 + quad*8 + j]
    const float* bptr = clu_feats + (size_t)(r0w + m) * D_FEAT + quad * 8;
    const float4 bL0 = *(const float4*)(bptr);
    const float4 bH0 = *(const float4*)(bptr + 4);
    const float4 bL1 = *(const float4*)(bptr + 32);
    const float4 bH1 = *(const float4*)(bptr + 36);

    // ---- stage centroid feats: fp32 -> bf16, fragment order, XOR-swizzled ----
    #pragma unroll
    for (int i = 0; i < 4; ++i) {
        const int q = t + i * THREADS;        // octet: centroid n, feature-octet o
        const int n = q >> 3, o = q & 7;
        const float4 g0 = ((const float4*)cen_feats)[q * 2];
        const float4 g1 = ((const float4*)cen_feats)[q * 2 + 1];
        uint4 d;
        d.x = pk2t(g0.x, g0.y); d.y = pk2t(g0.z, g0.w);
        d.z = pk2t(g1.x, g1.y); d.w = pk2t(g1.z, g1.w);
        const int tile = n >> 4;
        const int np   = n & 15;
        const int f    = o >> 2;
        const int lp   = (np | ((o & 3) << 4)) ^ o;   // XOR bank swizzle (r5-verified)
        ((uint4*)Bl)[(tile * 2 + f) * 64 + lp] = d;
    }
    // ---- stage centroid coord A-frags (quad-0 slots k0..7 of each row) ----
    if (t < N_CENTROIDS) {
        const int4 c = ((const int4*)cen_coords)[t];   // {b,x,y,z}
        const float gx = (float)c.y, gy = (float)c.z, gz = (float)c.w, gb = (float)c.x;
        const float cn = fmaf(gx, gx, fmaf(gy, gy, gz * gz));   // exact int
        const float hi = __uint_as_float(__float_as_uint(cn) & 0xFFFF0000u);
        const float lo = cn - hi;                               // int < 256, exact
        uint4 e;
        e.x = pk2t(-2.f * gx, -2.f * gy);
        e.y = pk2t(-2.f * gz, -262144.f * gb);      // -2W*b, W = 2^17
        e.z = pk2t(hi, lo);
        e.w = pk2t(131072.f * gb * gb, 1.0f);       // W*b^2 | 1
        Atab[t] = e;
    }

    // ---- this lane's cluster-coord B-frag (col = m) ----
    const int4 rc = ((const int4*)clu_coords)[r0w + m];   // {b,x,y,z}
    union { uint4 u; bf16x8 v; } bc;
    {
        const float px = (float)rc.y, py = (float)rc.z, pz = (float)rc.w, pb = (float)rc.x;
        const float pn  = fmaf(px, px, fmaf(py, py, pz * pz));  // exact int
        const float phi = __uint_as_float(__float_as_uint(pn) & 0xFFFF0000u);
        const float plo = pn - phi;                             // int < 256, exact
        uint4 q0, q1, zz;
        q0.x = pk2t(px, py);
        q0.y = pk2t(pz, pb);
        q0.z = 0x3F803F80u;                         // 1 | 1  (k4,k5)
        q0.w = pk2t(1.0f, phi);                     // 1 | pn_hi (k6,k7)
        q1.x = pk2t(plo, 131072.f * pb * pb);       // pn_lo | W*b^2 (k8,k9)
        q1.y = 0u; q1.z = 0u; q1.w = 0u;
        zz.x = 0u; zz.y = 0u; zz.z = 0u; zz.w = 0u;
        bc.u = (quad == 0) ? q0 : ((quad == 1) ? q1 : zz);
    }
    // A-frag lane masks: quad 0 reads Atab; quad 1 is [1,1,0,...]; quads 2,3 zero.
    const unsigned amsk = (quad == 0) ? 0xFFFFFFFFu : 0u;
    const unsigned aor  = (quad == 1) ? 0x3F803F80u : 0u;

    // ---- convert B frags to bf16 (perm-truncate) ----
    union { uint4 u; bf16x8 v; } b0, b1;
    b0.u.x = pk2t(bL0.x, bL0.y); b0.u.y = pk2t(bL0.z, bL0.w);
    b0.u.z = pk2t(bH0.x, bH0.y); b0.u.w = pk2t(bH0.z, bH0.w);
    b1.u.x = pk2t(bL1.x, bL1.y); b1.u.y = pk2t(bL1.z, bL1.w);
    b1.u.z = pk2t(bH1.x, bH1.y); b1.u.w = pk2t(bH1.z, bH1.w);

    __syncthreads();

    // ---- pass 1: d^2 via MFMA, then exp(-dist); packed 4 x f16 per reg;
    // f32 row sum. Masked (cross-batch) elements: d2 >= 2^17 -> exp == +0,
    // so rsum adds unconditionally; uu encodes mask in sign for pass 2. ----
    unsigned u16[16];
    float rsum = 0.f;
    #pragma unroll
    for (int tt = 0; tt < 16; ++tt) {
        const uint4 a = Atab[tt * 16 + m];          // b128 broadcast across quads
        union { uint4 u; bf16x8 v; } af;
        af.u.x = (a.x & amsk) | aor;
        af.u.y =  a.y & amsk;
        af.u.z =  a.z & amsk;
        af.u.w =  a.w & amsk;
        f32x4 d2 = {0.f, 0.f, 0.f, 0.f};
        d2 = __builtin_amdgcn_mfma_f32_16x16x32_bf16(af.v, bc.v, d2, 0, 0, 0);
        float uu[4];
        #pragma unroll
        for (int i = 0; i < 4; ++i) {
            const float dist = fmaxf(__builtin_sqrtf(d2[i]), 0.1f);
            const float e    = __expf(-dist);       // masked -> +0 exactly
            rsum += e;
            uu[i] = (d2[i] < TH_MASK) ? e : -1.0f;
        }
        u16[tt] = pk4h(uu[0], uu[1], uu[2], uu[3]);
    }
    // combine the 4 quads holding the same cluster (lanes m, m+16, m+32, m+48)
    rsum += __shfl_xor(rsum, 16, 64);
    rsum += __shfl_xor(rsum, 32, 64);
    // rcp guard: denormal sum -> rcp = inf -> 0*inf = NaN. Emit zeros instead.
    const float inv = (rsum > 1e-37f) ? __builtin_amdgcn_rcpf(rsum) : 0.f;

    // ---- pass 2: MFMA (A=centroids, B=clusters) + fused epilogue + float4
    // stores. acc[i] = dot(centroid tt*16+quad*4+i, cluster r0w+m). ----
    const int sl0 = lane ^ quad;              // inverse swizzle, frag 0
    const int sl1 = sl0 ^ 4;                  // frag 1
    float* obase = out + (size_t)(r0w + m) * N_CENTROIDS + quad * 4;

    #pragma unroll
    for (int tt = 0; tt < 16; ++tt) {
        const bf16x8 aC0 = *(const bf16x8*)&Bl[((tt * 2 + 0) * 64 + sl0) * 4];
        const bf16x8 aC1 = *(const bf16x8*)&Bl[((tt * 2 + 1) * 64 + sl1) * 4];
        f32x4 acc = {0.f, 0.f, 0.f, 0.f};
        acc = __builtin_amdgcn_mfma_f32_16x16x32_bf16(aC0, b0.v, acc, 0, 0, 0);
        acc = __builtin_amdgcn_mfma_f32_16x16x32_bf16(aC1, b1.v, acc, 0, 0, 0);

        const unsigned up = u16[tt];
        const unsigned uq = u16[tt] >> 16;
        float uu[4];
        uu[0] = h2f_lo(up); uu[1] = h2f_hi(up);
        uu[2] = h2f_lo(uq); uu[3] = h2f_hi(uq);
        float4 o;
        #pragma unroll
        for (int i = 0; i < 4; ++i) {
            float w = acc[i] * (fmaxf(uu[i], 0.f) * inv);
            w = fminf(fmaxf(w, -10.f), 10.f);
            (&o.x)[i] = (uu[i] < 0.f) ? MASK_VAL : w;
        }
        *(float4*)(obase + tt * 16) = o;
    }
}

extern "C" void kernel_launch(void* const* d_in, const int* in_sizes, int n_in,
                              void* d_out, int out_size, void* d_ws, size_t ws_size,
                              hipStream_t stream) {
    const int*   clu_coords = (const int*)  d_in[0];
    const float* clu_feats  = (const float*)d_in[1];
    const int*   cen_coords = (const int*)  d_in[2];
    const float* cen_feats  = (const float*)d_in[3];
    float* out = (float*)d_out;

    dim3 grid(N_CLUSTERS / ROWS_PER_BLOCK);   // 1024 blocks
    dim3 block(THREADS);                      // 512 threads = 8 waves
    instance_head_kernel<<<grid, block, 0, stream>>>(
        clu_coords, clu_feats, cen_coords, cen_feats, out);
}